// Round 10
// baseline (289.929 us; speedup 1.0000x reference)
//
#include <hip/hip_runtime.h>

typedef unsigned short u16;
typedef unsigned int u32;
typedef _Float16 half8 __attribute__((ext_vector_type(8)));
typedef __fp16 fp16x2 __attribute__((ext_vector_type(2)));
typedef float f32x16 __attribute__((ext_vector_type(16)));

union HU { uint4 u; half8 h; };
union PK { fp16x2 h; u32 u; };

__device__ __forceinline__ u16 f2h(float f) {
  union { _Float16 h; u16 u; } c;
  c.h = (_Float16)f;
  return c.u;
}

// async global->LDS DMA, 16 B per lane (lds dest = wave-uniform base + lane*16)
typedef const __attribute__((address_space(1))) u32 gu32;
typedef __attribute__((address_space(3))) u32 lu32;
__device__ __forceinline__ void gload_lds16(const void* g, void* l) {
  __builtin_amdgcn_global_load_lds((gu32*)g, (lu32*)l, 16, 0, 0);
}

// Pack weights (O=64, I=64, 3, 3) fp32 -> fp16 in exact A-fragment order:
// wbuf[((t*2 + mt)*64 + lane)*8 + j] = w[m][c][rs]
//   m = mt*32 + (lane&31), k = t*16 + (lane>>5)*8 + j, rs = k>>6, c = k&63
// K ordering: k = rs*64 + c (rs-major, c-minor); ktile t = rs*4 + Q (16-ch quarter).
__global__ void prep_w(const float* __restrict__ w, u16* __restrict__ wbuf) {
  int idx = blockIdx.x * 256 + threadIdx.x;  // 36864 total
  int j    = idx & 7;
  int lane = (idx >> 3) & 63;
  int mt   = (idx >> 9) & 1;
  int t    = idx >> 10;
  int m  = mt * 32 + (lane & 31);
  int k  = t * 16 + (lane >> 5) * 8 + j;
  int rs = k >> 6;
  int c  = k & 63;
  wbuf[idx] = f2h(w[(m * 64 + c) * 9 + rs]);
}

// Pre-convert + pre-transpose x with HALO PADDING on both axes:
//   xp[(((nb*130 + hrow)*8 + cblk)*130 + slot)*8 + j]
//     = (hrow in 1..128 && slot in 1..128) ? fp16(x[nb][cblk*8+j][hrow-1][slot-1]) : 0
// 16 B = one pixel's 8-channel fp16 group = exactly one MFMA B-fragment lane
// chunk, so the conv kernel can load B operands DIRECTLY from global memory
// (coalesced across l31, L1-cached across the 3 kw shifts, L3-resident).
// Padded rows/slots make the conv 100% bounds-logic-free.
// Reads: 8 channel-strided float4 streams (512 B segments, coalesced).
// Writes: 64 B/thread contiguous (2 KB per 32-lane group).
__global__ __launch_bounds__(256) void prep_x(const float* __restrict__ x,
                                              u16* __restrict__ xp) {
  int bid = blockIdx.x;         // 32*130: nb*130 + hrow
  int nb = bid / 130, hrow = bid - nb * 130;
  int tid = threadIdx.x;
  u16* orow = xp + (size_t)(nb * 130 + hrow) * (8 * 130 * 8);
  const uint4 zz = make_uint4(0u, 0u, 0u, 0u);
  if (hrow == 0 || hrow == 129) {   // halo row: 16,640 B of zeros
#pragma unroll
    for (int s = 0; s < 5; ++s) {
      int i = s * 256 + tid;
      if (i < 1040) ((uint4*)orow)[i] = zz;
    }
    return;
  }
  int h = hrow - 1;
  int cblk = tid >> 5;          // 0..7
  int px4 = (tid & 31) * 4;     // 0..124
  const float* xb = x + (((size_t)(nb * 64 + cblk * 8) * 128 + h) * 128 + px4);
  float4 f[8];
#pragma unroll
  for (int j = 0; j < 8; ++j) f[j] = *(const float4*)(xb + (size_t)j * 16384);
  u16* ob = orow + (cblk * 130 + 1 + px4) * 8;  // slot = px + 1
#pragma unroll
  for (int p = 0; p < 4; ++p) {
    PK q0, q1, q2, q3;
    q0.h = __builtin_amdgcn_cvt_pkrtz(((const float*)&f[0])[p], ((const float*)&f[1])[p]);
    q1.h = __builtin_amdgcn_cvt_pkrtz(((const float*)&f[2])[p], ((const float*)&f[3])[p]);
    q2.h = __builtin_amdgcn_cvt_pkrtz(((const float*)&f[4])[p], ((const float*)&f[5])[p]);
    q3.h = __builtin_amdgcn_cvt_pkrtz(((const float*)&f[6])[p], ((const float*)&f[7])[p]);
    *(uint4*)(ob + p * 8) = make_uint4(q0.u, q1.u, q2.u, q3.u);
  }
  // pixel halo slots 0 and 129 of this (row, cblk)
  if ((tid & 31) == 0)  *(uint4*)(orow + (cblk * 130 + 0) * 8)   = zz;
  if ((tid & 31) == 31) *(uint4*)(orow + (cblk * 130 + 129) * 8) = zz;
}

// Implicit-GEMM conv: M = O = 64, N = pixels, K = 576 in 4 quarters of 16 ch.
// v10: B DIRECT FROM GLOBAL. Round 9 proved removing in-kernel staging drops
// conv below ~78 us (first time under the harness fill kernels); the residual
// costs were x-LDS dbuf (70 KB -> 2 blocks/CU) + dma_x windows + prep_x.
// Since padded xp is already in exact B-fragment order, x never touches LDS:
//   kloop ktile = {2 A ds_read_b128 (wlds) + 2 B global_load_dwordx4 (xp)
//                  + 4 MFMA}, zero bounds logic (halo-padded rows AND slots).
// B loads are lane-coalesced 1 KB/instr, L1-hit across the 3 kw shifts
// (+16 B), L3-resident (xp = 69 MB just written by prep_x).
// LDS = w dbuf only, 2 x 18,432 B = 36,864 -> LDS allows 4 blocks/CU;
// launch_bounds(256,3) -> 170-reg budget (acc 64 + frags + ~50 slack for
// compiler load-pipelining; no spill — WRITE_SIZE is the tell), 3 blocks/CU.
// Block = 2 output rows x 128 px x 64 o, 4 waves = (rw2, np2), grid 2048.
// Wave computes 64o x 64px, acc[2][2] (1.0 LDS-read/MFMA on A only).
// 4 barriers total; dma_w(Q+1) issues before kloop(Q) (fire-and-forget).
// XCD swizzle: 2048 % 8 == 0; wg = (bid&7)*256 + bid>>3.
__global__ __launch_bounds__(256, 3) void conv_mfma(
    const u16* __restrict__ xp, const u16* __restrict__ wbuf,
    const float* __restrict__ bias, float* __restrict__ out) {
  __shared__ u16 wlds[2][18 * 512];  // 2 x 18,432 B

  int tid = threadIdx.x;
  int lane = tid & 63;
  int wave = tid >> 6;  // 0..3
  int bid = blockIdx.x;
  int wg = ((bid & 7) << 8) | (bid >> 3);  // bijective XCD-contiguous remap
  int nb = wg >> 6;        // batch [0,32)
  int hg = wg & 63;        // row-group [0,64)
  int h0 = hg * 2;

  int l31 = lane & 31;
  int half = lane >> 5;
  int rw = wave >> 1;   // output row within block (0..1)
  int np = wave & 1;    // ntile pair: pixels np*64 + {0,32} + l31

  f32x16 acc[2][2] = {};  // [mt][ntile]

  // DMA quarter Q's 18 A-fragments (rs9 x mt2, 1 KB each) into wl.
  auto dma_w = [&](int Q, u16* wl) {
#pragma unroll
    for (int s5 = 0; s5 < 5; ++s5) {
      int f = s5 * 4 + wave;  // 0..19, valid < 18
      if (f < 18) {
        int gf = (f >> 1) * 8 + Q * 2 + (f & 1);  // wbuf frag (rs*4+Q)*2+mt
        gload_lds16(&wbuf[gf * 512 + lane * 8], &wl[f * 512]);
      }
    }
  };

  // 9 ktiles: {2 A ds_read + 2 B global b128 + 4 MFMA}; no bounds logic.
  auto kloop = [&](int Q, const u16* wl) {
#pragma unroll
    for (int r = 0; r < 3; ++r) {
      // padded row index = (h0-1+rw+r)+1 = h0+rw+r, always in [0,129]
      const u16* xr = xp + ((((size_t)(nb * 130) + (h0 + rw + r)) * 8 +
                             (Q * 2 + half)) * 130 + np * 64 + l31) * 8;
#pragma unroll
      for (int s = 0; s < 3; ++s) {
        int rs = r * 3 + s;
        HU a0, a1, b0, b1;
        a0.u = *(const uint4*)&wl[(rs * 2 + 0) * 512 + lane * 8];
        a1.u = *(const uint4*)&wl[(rs * 2 + 1) * 512 + lane * 8];
        b0.u = *(const uint4*)(xr + s * 8);          // slot np*64+l31+s
        b1.u = *(const uint4*)(xr + s * 8 + 256);    // +32 slots (ntile 1)
        acc[0][0] = __builtin_amdgcn_mfma_f32_32x32x16_f16(a0.h, b0.h, acc[0][0], 0, 0, 0);
        acc[0][1] = __builtin_amdgcn_mfma_f32_32x32x16_f16(a0.h, b1.h, acc[0][1], 0, 0, 0);
        acc[1][0] = __builtin_amdgcn_mfma_f32_32x32x16_f16(a1.h, b0.h, acc[1][0], 0, 0, 0);
        acc[1][1] = __builtin_amdgcn_mfma_f32_32x32x16_f16(a1.h, b1.h, acc[1][1], 0, 0, 0);
      }
    }
  };

  // ---- schedule: w dbuf DMA pipelined across quarters; x needs no staging ----
  dma_w(0, wlds[0]);
  __syncthreads();  // drains DMA (compiler emits vmcnt(0) before barrier)
#pragma unroll
  for (int Q = 0; Q < 4; ++Q) {
    if (Q < 3) dma_w(Q + 1, wlds[(Q + 1) & 1]);  // fire-and-forget
    kloop(Q, wlds[Q & 1]);
    if (Q < 3) __syncthreads();  // DMA completed under kloop; buffers safe
  }

  // ---- epilogue: C/D layout col = lane&31 (pixel), row = (reg&3)+8*(reg>>2)+4*half (o) ----
  int h = h0 + rw;
#pragma unroll
  for (int mt = 0; mt < 2; ++mt) {
#pragma unroll
    for (int i = 0; i < 2; ++i) {
      int p = np * 64 + i * 32 + l31;
      size_t ob = (size_t)nb * 64 * 16384 + (size_t)h * 128 + p;
#pragma unroll
      for (int reg = 0; reg < 16; ++reg) {
        int o = mt * 32 + (reg & 3) + 8 * (reg >> 2) + 4 * half;
        out[ob + (size_t)o * 16384] = acc[mt][i][reg] + bias[o];
      }
    }
  }
}

extern "C" void kernel_launch(void* const* d_in, const int* in_sizes, int n_in,
                              void* d_out, int out_size, void* d_ws, size_t ws_size,
                              hipStream_t stream) {
  const float* x = (const float*)d_in[0];
  const float* w = (const float*)d_in[1];
  const float* b = (const float*)d_in[2];
  float* out = (float*)d_out;
  // workspace: wbuf (73,728 B) at 0; padded xp (69.2 MB) at 128 KB offset.
  u16* wbuf = (u16*)d_ws;
  u16* xp = (u16*)((char*)d_ws + (128 << 10));

  prep_w<<<dim3(144), dim3(256), 0, stream>>>(w, wbuf);
  prep_x<<<dim3(32 * 130), dim3(256), 0, stream>>>(x, xp);
  conv_mfma<<<dim3(2048), dim3(256), 0, stream>>>(xp, wbuf, b, out);
}